// Round 8
// baseline (2143.813 us; speedup 1.0000x reference)
//
#include <hip/hip_runtime.h>
#include <hip/hip_bf16.h>
#include <math.h>

#define BB 4
#define NDET 128
#define NT 2048
#define DD 256
#define LL 6
#define MROWS 1024
#define GRID 496

typedef __attribute__((ext_vector_type(8))) short s8v;
typedef __attribute__((ext_vector_type(4))) float f32x4;
typedef unsigned short ushort_t;

__device__ __forceinline__ unsigned short f2b(float x) {
  union { float f; unsigned u; } v; v.f = x;
  unsigned r = v.u + 0x7fff + ((v.u >> 16) & 1);
  return (unsigned short)(r >> 16);
}
__device__ __forceinline__ unsigned pk2(float a, float b) {
  return (unsigned)f2b(a) | ((unsigned)f2b(b) << 16);
}
__device__ __forceinline__ float gelu_exact(float x) {
  return 0.5f * x * (1.0f + erff(x * 0.70710678118654752f));
}

// ---------------- hierarchical grid barrier ----------------
// bar[g*16], g<64 : arrival counters (cumulative), 8 blocks/group
// bar[1024 + x*16], x<8 : per-XCD epoch words
__device__ __forceinline__ void gsync(unsigned* bar, int s) {
  __syncthreads();
  int tid = threadIdx.x;
  unsigned bid = blockIdx.x;
  if (tid == 0) {
    __hip_atomic_fetch_add(&bar[(bid & 63) * 16], 1u, __ATOMIC_ACQ_REL,
                           __HIP_MEMORY_SCOPE_AGENT);
  }
  if (bid == 0) {
    if (tid < 64) {
      unsigned tgt = (tid < 48 ? 8u : 7u) * (unsigned)(s + 1);
      while (__hip_atomic_load(&bar[tid * 16], __ATOMIC_ACQUIRE,
                               __HIP_MEMORY_SCOPE_AGENT) < tgt)
        __builtin_amdgcn_s_sleep(4);
    }
    __syncthreads();
    if (tid < 8)
      __hip_atomic_store(&bar[1024 + tid * 16], (unsigned)(s + 1),
                         __ATOMIC_RELEASE, __HIP_MEMORY_SCOPE_AGENT);
  } else {
    if (tid == 0) {
      while (__hip_atomic_load(&bar[1024 + (bid & 7) * 16], __ATOMIC_ACQUIRE,
                               __HIP_MEMORY_SCOPE_AGENT) < (unsigned)(s + 1))
        __builtin_amdgcn_s_sleep(8);
    }
  }
  __syncthreads();
}

// ---------------- prep: weight casts + sino transpose ----------------
__global__ __launch_bounds__(256) void cast_all(
    const float* __restrict__ s0, const float* __restrict__ s1,
    const float* __restrict__ s2, const float* __restrict__ s3,
    const float* __restrict__ s4, const float* __restrict__ s5,
    unsigned short* __restrict__ d0, unsigned short* __restrict__ d1,
    unsigned short* __restrict__ d2, unsigned short* __restrict__ d3,
    unsigned short* __restrict__ d4, unsigned short* __restrict__ d5,
    const float* __restrict__ sino, float* __restrict__ st)
{
  const int e0 = 16384, e1 = 311296, e2 = 409600, e3 = 802816, e4 = 1196032,
            e5 = 1212416, e6 = 1474560;
  int i = blockIdx.x * 256 + threadIdx.x;
  int stride = gridDim.x * 256;
  for (; i < e6; i += stride) {
    if (i < e5) {
      const float* s; unsigned short* d; int j;
      if (i < e0)      { s = s0; d = d0; j = i; }
      else if (i < e1) { s = s1; d = d1; j = i - e0; }
      else if (i < e2) { s = s2; d = d2; j = i - e1; }
      else if (i < e3) { s = s3; d = d3; j = i - e2; }
      else if (i < e4) { s = s4; d = d4; j = i - e3; }
      else             { s = s5; d = d5; j = i - e4; }
      float4 f = ((const float4*)s)[j];
      uint2 uv;
      uv.x = pk2(f.x, f.y);
      uv.y = pk2(f.z, f.w);
      ((uint2*)d)[j] = uv;
    } else {
      int idx = i - e5;
      float4 v;
      v.x = sino[idx];
      v.y = sino[262144 + idx];
      v.z = sino[524288 + idx];
      v.w = sino[786432 + idx];
      ((float4*)st)[idx] = v;
    }
  }
}

// ---------------- backprojection: XCD-pinned detector chunks --------------
__global__ __launch_bounds__(256) void bp_part(
    const float* __restrict__ st, const float* __restrict__ lut,
    float* __restrict__ partial)
{
  __shared__ float apod[NDET];
  int tid = threadIdx.x;
  if (tid < NDET) {
    float ap = 0.5f - 0.5f * cosf(6.283185307179586f * (float)tid / 127.0f);
    apod[tid] = ap * (1.0f / 63.5f);
  }
  __syncthreads();
  int c = blockIdx.x & 7;
  int pb = blockIdx.x >> 3;
  int pix = pb * 256 + tid;
  const float* lrow = lut + (size_t)pix * 256;
  const float4* sp = (const float4*)st;
  float a0 = 0.f, a1 = 0.f, a2 = 0.f, a3 = 0.f;
#pragma unroll
  for (int d0 = c * 16; d0 < c * 16 + 16; d0 += 4) {
    float4 l0 = *(const float4*)(lrow + d0 * 2);
    float4 l1 = *(const float4*)(lrow + d0 * 2 + 4);
    float kfs[4] = {l0.x, l0.z, l1.x, l1.z};
    float als[4] = {l0.y, l0.w, l1.y, l1.w};
#pragma unroll
    for (int dd = 0; dd < 4; ++dd) {
      int kf = (int)kfs[dd];
      if (kf >= 0 && kf < NT - 1) {
        float al = als[dd];
        float ap = apod[d0 + dd];
        float w0 = (1.0f - al) * ap, w1 = al * ap;
        const float4* q = sp + (d0 + dd) * NT + kf;
        float4 s0 = q[0], s1 = q[1];
        a0 += w0 * s0.x + w1 * s1.x;
        a1 += w0 * s0.y + w1 * s1.y;
        a2 += w0 * s0.z + w1 * s1.z;
        a3 += w0 * s0.w + w1 * s1.w;
      }
    }
  }
  partial[(size_t)(c * 4 + 0) * 65536 + pix] = a0;
  partial[(size_t)(c * 4 + 1) * 65536 + pix] = a1;
  partial[(size_t)(c * 4 + 2) * 65536 + pix] = a2;
  partial[(size_t)(c * 4 + 3) * 65536 + pix] = a3;
}

// ---------------- GEMM phase: TM x 64 tiles, full-K LDS panels ------------
// AMODE: 0 fp32 A, 1 gather bp image, 2 LN(A) fused, 3 bf16 A
// OMODE: 0 fp32 out, 1 scatter to image, 2 bf16 out
template<int ACT, int RES, int AMODE, int OMODE, int TM>
__device__ __forceinline__ void gemm_phase(
    char* smem, int tid,
    const float* __restrict__ A, const unsigned short* __restrict__ A16,
    const unsigned short* __restrict__ Wb,
    const float* __restrict__ bias, const float* __restrict__ res,
    const float* __restrict__ lng, const float* __restrict__ lnb,
    float* __restrict__ C, unsigned short* __restrict__ C16,
    int ntm, int ntn, int N, int K, int res_mask)
{
  constexpr int RI = TM / 32;
  typedef unsigned short Us264[264];
  Us264* As = (Us264*)smem;                       // TM rows
  Us264* Bs = (Us264*)(smem + TM * 264 * 2);      // 64 rows
  int lane = tid & 63, w = tid >> 6;
  int lr = lane & 15, hi = lane >> 4;
  int lk = hi * 8, lg = hi * 4;
  int wr = (w & 1) * 16 * RI, wc = (w >> 1) * 32;
  int ntiles = ntm * ntn;
  for (int t = blockIdx.x; t < ntiles; t += GRID) {
    int bm = (t / ntn) * TM, bn = (t % ntn) * 64;
    f32x4 acc[RI][2];
#pragma unroll
    for (int i = 0; i < RI; ++i)
#pragma unroll
      for (int j = 0; j < 2; ++j) acc[i][j] = (f32x4){0.f, 0.f, 0.f, 0.f};
    for (int kc = 0; kc < K; kc += 256) {
      __syncthreads();
      // ---- stage A panel TM x 256 ----
      if (AMODE == 2) {
        float4 gl = ((const float4*)lng)[lane];
        float4 bl = ((const float4*)lnb)[lane];
#pragma unroll
        for (int rr = 0; rr < TM / 4; ++rr) {
          int row = w * (TM / 4) + rr;
          float4 v = ((const float4*)(A + (size_t)(bm + row) * 256))[lane];
          float s = v.x + v.y + v.z + v.w;
#pragma unroll
          for (int off = 32; off; off >>= 1) s += __shfl_xor(s, off);
          float mean = s * (1.0f / 256.0f);
          float q = (v.x - mean) * (v.x - mean) + (v.y - mean) * (v.y - mean) +
                    (v.z - mean) * (v.z - mean) + (v.w - mean) * (v.w - mean);
#pragma unroll
          for (int off = 32; off; off >>= 1) q += __shfl_xor(q, off);
          float inv = 1.0f / sqrtf(q * (1.0f / 256.0f) + 1e-5f);
          float y0 = (v.x - mean) * inv * gl.x + bl.x;
          float y1 = (v.y - mean) * inv * gl.y + bl.y;
          float y2 = (v.z - mean) * inv * gl.z + bl.z;
          float y3 = (v.w - mean) * inv * gl.w + bl.w;
          uint2 u2; u2.x = pk2(y0, y1); u2.y = pk2(y2, y3);
          *(uint2*)&As[row][lane * 4] = u2;
        }
      } else if (AMODE == 3) {
        constexpr int TPR = 256 / TM;            // threads per row
        int r = tid / TPR, cb = (tid % TPR) * (256 / TPR);
        const unsigned short* ap = A16 + (size_t)(bm + r) * K + kc + cb;
#pragma unroll
        for (int q8 = 0; q8 < 32 / TPR; ++q8)
          *(uint4*)&As[r][cb + q8 * 8] = *(const uint4*)(ap + q8 * 8);
      } else {
        constexpr int TPR = 256 / TM;
        int r = tid / TPR, cb = (tid % TPR) * (256 / TPR);
#pragma unroll
        for (int q8 = 0; q8 < 32 / TPR; ++q8) {
          int k = cb + q8 * 8;
          float4 f0, f1;
          if (AMODE == 0) {
            const float* ap = A + (size_t)(bm + r) * K + kc + k;
            f0 = *(const float4*)ap;
            f1 = *(const float4*)(ap + 4);
          } else {
            int m = bm + r;
            int bb = m >> 8, nn = m & 255;
            int k2 = k + 4;
            f0 = *(const float4*)(A + (size_t)bb * 65536 +
                 ((nn >> 4) * 16 + (k >> 4)) * 256 + (nn & 15) * 16 + (k & 15));
            f1 = *(const float4*)(A + (size_t)bb * 65536 +
                 ((nn >> 4) * 16 + (k2 >> 4)) * 256 + (nn & 15) * 16 + (k2 & 15));
          }
          uint4 u;
          u.x = pk2(f0.x, f0.y); u.y = pk2(f0.z, f0.w);
          u.z = pk2(f1.x, f1.y); u.w = pk2(f1.z, f1.w);
          *(uint4*)&As[r][k] = u;
        }
      }
      // ---- stage B panel 64 x 256 ----
      {
        int r = tid >> 2, cb = (tid & 3) * 64;
        const unsigned short* wp = Wb + (size_t)(bn + r) * K + kc + cb;
#pragma unroll
        for (int q8 = 0; q8 < 8; ++q8)
          *(uint4*)&Bs[r][cb + q8 * 8] = *(const uint4*)(wp + q8 * 8);
      }
      __syncthreads();
      // ---- MFMA over the panel ----
#pragma unroll
      for (int k0 = 0; k0 < 256; k0 += 32) {
        s8v b0 = *(const s8v*)&Bs[wc + lr][k0 + lk];
        s8v b1 = *(const s8v*)&Bs[wc + 16 + lr][k0 + lk];
#pragma unroll
        for (int i = 0; i < RI; ++i) {
          s8v a = *(const s8v*)&As[wr + i * 16 + lr][k0 + lk];
          acc[i][0] = __builtin_amdgcn_mfma_f32_16x16x32_bf16(a, b0, acc[i][0], 0, 0, 0);
          acc[i][1] = __builtin_amdgcn_mfma_f32_16x16x32_bf16(a, b1, acc[i][1], 0, 0, 0);
        }
      }
    }
#pragma unroll
    for (int i = 0; i < RI; ++i)
#pragma unroll
      for (int j = 0; j < 2; ++j) {
        int n = bn + wc + j * 16 + lr;
        float bv = bias[n];
#pragma unroll
        for (int r4 = 0; r4 < 4; ++r4) {
          int m = bm + wr + i * 16 + lg + r4;
          float c = acc[i][j][r4] + bv;
          if (ACT == 1) c = gelu_exact(c);
          if (RES == 1) c += res[(size_t)(m & res_mask) * N + n];
          if (OMODE == 0) {
            C[(size_t)m * N + n] = c;
          } else if (OMODE == 1) {
            int bb = m >> 8, t2 = m & 255;
            C[(size_t)bb * 65536 + ((t2 >> 4) * 16 + (n >> 4)) * 256 +
              (t2 & 15) * 16 + (n & 15)] = c;
          } else {
            C16[(size_t)m * N + n] = f2b(c);
          }
        }
      }
  }
}

// ---------------- attention phase ----------------
__device__ __forceinline__ void attn_phase(
    char* smem, int tid,
    const unsigned short* __restrict__ qkv, unsigned short* __restrict__ o16)
{
  typedef unsigned short Us40[40];
  typedef unsigned short Us264[264];
  Us40* Kl = (Us40*)smem;                        // 20480
  Us40* Qb = (Us40*)(smem + 20480);              // 2560
  Us264* Vt = (Us264*)(smem + 23040);            // 16896
  float (*Sf)[268] = (float(*)[268])(smem + 39936);  // 34304
  Us264* Pl = (Us264*)(smem + 39936);            // aliases Sf
  int lane = tid & 63, w = tid >> 6;
  int lr = lane & 15, hi = lane >> 4;
  int lk = hi * 8, lg = hi * 4;

  for (int u = blockIdx.x; u < 256; u += GRID) {
    int qc = u & 7, h = (u >> 3) & 7, b = u >> 6;
    const unsigned short* base = qkv + (size_t)b * 256 * 768;
    __syncthreads();
    {
      const unsigned short* kr = base + tid * 768 + 256 + h * 32;
#pragma unroll
      for (int cq = 0; cq < 4; ++cq)
        *(uint4*)&Kl[tid][cq * 8] = *(const uint4*)(kr + cq * 8);
      const unsigned short* vr = base + tid * 768 + 512 + h * 32;
      unsigned short tmp[32];
#pragma unroll
      for (int cq = 0; cq < 4; ++cq)
        *(uint4*)&tmp[cq * 8] = *(const uint4*)(vr + cq * 8);
#pragma unroll
      for (int cc = 0; cc < 32; ++cc) Vt[cc][tid] = tmp[cc];
      int row = tid >> 3, c0 = (tid & 7) * 4;
      *(uint2*)&Qb[row][c0] =
          *(const uint2*)(base + (qc * 32 + row) * 768 + h * 32 + c0);
    }
    __syncthreads();
    {
      s8v qa0 = *(const s8v*)&Qb[lr][lk];
      s8v qa1 = *(const s8v*)&Qb[16 + lr][lk];
      f32x4 z4 = (f32x4){0.f, 0.f, 0.f, 0.f};
#pragma unroll
      for (int j = 0; j < 4; ++j) {
        s8v kb = *(const s8v*)&Kl[w * 64 + j * 16 + lr][lk];
        f32x4 s0 = __builtin_amdgcn_mfma_f32_16x16x32_bf16(qa0, kb, z4, 0, 0, 0);
        f32x4 s1 = __builtin_amdgcn_mfma_f32_16x16x32_bf16(qa1, kb, z4, 0, 0, 0);
#pragma unroll
        for (int r4 = 0; r4 < 4; ++r4) {
          Sf[lg + r4][w * 64 + j * 16 + lr] = s0[r4];
          Sf[16 + lg + r4][w * 64 + j * 16 + lr] = s1[r4];
        }
      }
    }
    __syncthreads();
    float vv[8][4];
    {
      const float scale = 0.17677669529663687f;
#pragma unroll
      for (int rr = 0; rr < 8; ++rr) {
        int row = w * 8 + rr;
        float4 v = *(const float4*)&Sf[row][lane * 4];
        v.x *= scale; v.y *= scale; v.z *= scale; v.w *= scale;
        float mx = fmaxf(fmaxf(v.x, v.y), fmaxf(v.z, v.w));
#pragma unroll
        for (int off = 32; off; off >>= 1) mx = fmaxf(mx, __shfl_xor(mx, off));
        float e0 = expf(v.x - mx), e1 = expf(v.y - mx);
        float e2 = expf(v.z - mx), e3 = expf(v.w - mx);
        float ss = e0 + e1 + e2 + e3;
#pragma unroll
        for (int off = 32; off; off >>= 1) ss += __shfl_xor(ss, off);
        float inv = 1.0f / ss;
        vv[rr][0] = e0 * inv; vv[rr][1] = e1 * inv;
        vv[rr][2] = e2 * inv; vv[rr][3] = e3 * inv;
      }
    }
    __syncthreads();
#pragma unroll
    for (int rr = 0; rr < 8; ++rr) {
      int row = w * 8 + rr;
      uint2 u2;
      u2.x = pk2(vv[rr][0], vv[rr][1]);
      u2.y = pk2(vv[rr][2], vv[rr][3]);
      *(uint2*)&Pl[row][lane * 4] = u2;
    }
    __syncthreads();
    {
      int wr = (w & 1) * 16, wc2 = (w >> 1) * 16;
      f32x4 oa = (f32x4){0.f, 0.f, 0.f, 0.f};
#pragma unroll
      for (int ks = 0; ks < 8; ++ks) {
        s8v pa = *(const s8v*)&Pl[wr + lr][ks * 32 + lk];
        s8v vb = *(const s8v*)&Vt[wc2 + lr][ks * 32 + lk];
        oa = __builtin_amdgcn_mfma_f32_16x16x32_bf16(pa, vb, oa, 0, 0, 0);
      }
#pragma unroll
      for (int r4 = 0; r4 < 4; ++r4) {
        int row = qc * 32 + wr + lg + r4;
        o16[((size_t)(b * 256) + row) * 256 + h * 32 + wc2 + lr] = f2b(oa[r4]);
      }
    }
  }
}

// ---------------- mega kernel v2 ----------------
__global__ __launch_bounds__(256) void mega2(
    const float* __restrict__ partial, float* __restrict__ bpb,
    float* __restrict__ out_bp,
    const unsigned short* __restrict__ pwb, const float* __restrict__ patch_b,
    const float* __restrict__ pos,
    const float* __restrict__ ln1_g, const float* __restrict__ ln1_b,
    const unsigned short* __restrict__ qkvw, const float* __restrict__ bqkv,
    const unsigned short* __restrict__ wow, const float* __restrict__ bo,
    const float* __restrict__ ln2_g, const float* __restrict__ ln2_b,
    const unsigned short* __restrict__ w1w, const float* __restrict__ b1,
    const unsigned short* __restrict__ w2w, const float* __restrict__ b2,
    const unsigned short* __restrict__ projw, const float* __restrict__ proj_b,
    const float* __restrict__ conv_w, const float* __restrict__ conv_b,
    float* __restrict__ z, unsigned short* __restrict__ qkvb16,
    unsigned short* __restrict__ ob16, unsigned short* __restrict__ hb16,
    float* __restrict__ imgp, float* __restrict__ out,
    unsigned* __restrict__ bar)
{
  __shared__ __align__(16) char smem[74240];
  int tid = threadIdx.x;
  int sc = 0;

  // phase 0: bp reduce (also writes bp_img output)
  for (int pix = blockIdx.x * 256 + tid; pix < 65536; pix += GRID * 256) {
#pragma unroll
    for (int b = 0; b < 4; ++b) {
      float s = 0.f;
#pragma unroll
      for (int c = 0; c < 8; ++c)
        s += partial[(size_t)(c * 4 + b) * 65536 + pix];
      bpb[b * 65536 + pix] = s;
      out_bp[b * 65536 + pix] = s;
    }
  }
  gsync(bar, sc++);

  // patch embed + pos
  gemm_phase<0, 1, 1, 0, 64>(smem, tid, bpb, nullptr, pwb, patch_b, pos,
                             nullptr, nullptr, z, nullptr, 16, 4, 256, 256, 255);
  gsync(bar, sc++);

  for (int l = 0; l < LL; ++l) {
    gemm_phase<0, 0, 2, 2, 64>(smem, tid, z, nullptr,
                               qkvw + (size_t)l * 196608, bqkv + l * 768,
                               nullptr, ln1_g + l * 256, ln1_b + l * 256,
                               nullptr, qkvb16, 16, 12, 768, 256, 0);
    gsync(bar, sc++);
    attn_phase(smem, tid, qkvb16, ob16);
    gsync(bar, sc++);
    gemm_phase<0, 1, 3, 0, 64>(smem, tid, nullptr, ob16,
                               wow + (size_t)l * 65536, bo + l * 256, z,
                               nullptr, nullptr, z, nullptr, 16, 4, 256, 256, 1023);
    gsync(bar, sc++);
    gemm_phase<1, 0, 2, 2, 64>(smem, tid, z, nullptr,
                               w1w + (size_t)l * 262144, b1 + l * 1024,
                               nullptr, ln2_g + l * 256, ln2_b + l * 256,
                               nullptr, hb16, 16, 16, 1024, 256, 0);
    gsync(bar, sc++);
    gemm_phase<0, 1, 3, 0, 64>(smem, tid, nullptr, hb16,
                               w2w + (size_t)l * 262144, b2 + l * 256, z,
                               nullptr, nullptr, z, nullptr, 16, 4, 256, 1024, 1023);
    gsync(bar, sc++);
  }

  gemm_phase<0, 0, 0, 1, 64>(smem, tid, z, nullptr, projw, proj_b, nullptr,
                             nullptr, nullptr, imgp, nullptr, 16, 4, 256, 256, 0);
  gsync(bar, sc++);

  // conv 3x3 + conv_b + bp residual
  for (int gid = blockIdx.x * 256 + tid; gid < 262144; gid += GRID * 256) {
    int b = gid >> 16, rem = gid & 65535;
    int y = rem >> 8, x = rem & 255;
    const float* ip = imgp + (size_t)b * 65536;
    float s = conv_b[0];
#pragma unroll
    for (int dy = -1; dy <= 1; ++dy)
#pragma unroll
      for (int dx = -1; dx <= 1; ++dx) {
        int yy = y + dy, xx = x + dx;
        if (yy >= 0 && yy < 256 && xx >= 0 && xx < 256)
          s += conv_w[(dy + 1) * 3 + (dx + 1)] * ip[yy * 256 + xx];
      }
    out[gid] = s + bpb[gid];
  }
}

extern "C" void kernel_launch(void* const* d_in, const int* in_sizes, int n_in,
                              void* d_out, int out_size, void* d_ws, size_t ws_size,
                              hipStream_t stream) {
  const float* sino    = (const float*)d_in[0];
  const float* lut     = (const float*)d_in[1];
  const float* patch_w = (const float*)d_in[2];
  const float* patch_b = (const float*)d_in[3];
  const float* pos     = (const float*)d_in[4];
  const float* ln1_g   = (const float*)d_in[5];
  const float* ln1_b   = (const float*)d_in[6];
  const float* wqkv    = (const float*)d_in[7];
  const float* bqkv    = (const float*)d_in[8];
  const float* wo      = (const float*)d_in[9];
  const float* bo      = (const float*)d_in[10];
  const float* ln2_g   = (const float*)d_in[11];
  const float* ln2_b   = (const float*)d_in[12];
  const float* w1      = (const float*)d_in[13];
  const float* b1      = (const float*)d_in[14];
  const float* w2      = (const float*)d_in[15];
  const float* b2      = (const float*)d_in[16];
  const float* proj_w  = (const float*)d_in[17];
  const float* proj_b  = (const float*)d_in[18];
  const float* conv_w  = (const float*)d_in[19];
  const float* conv_b  = (const float*)d_in[20];
  float* out = (float*)d_out;
  float* ws  = (float*)d_ws;

  // fp32 scratch
  float* bpb     = ws;                   // 262144
  float* z       = bpb + 262144;         // 262144
  float* imgp    = z + 262144;           // 262144
  float* partial = imgp + 262144;        // 2097152
  float* st      = partial + 2097152;    // 1048576
  // bf16 region
  unsigned short* wsu    = (unsigned short*)(st + 1048576);
  unsigned short* pwb    = wsu;                 // 65536
  unsigned short* qkvw   = pwb + 65536;         // 1179648
  unsigned short* wow    = qkvw + 1179648;      // 393216
  unsigned short* w1w    = wow + 393216;        // 1572864
  unsigned short* w2w    = w1w + 1572864;       // 1572864
  unsigned short* projw  = w2w + 1572864;       // 65536
  unsigned short* qkvb16 = projw + 65536;       // 786432
  unsigned short* hb16   = qkvb16 + 786432;     // 1048576
  unsigned short* ob16   = hb16 + 1048576;      // 262144
  unsigned* bar = (unsigned*)(ob16 + 262144);   // 1152 uints

  hipMemsetAsync(bar, 0, 1152 * sizeof(unsigned), stream);

  cast_all<<<2048, 256, 0, stream>>>(patch_w, wqkv, wo, w1, w2, proj_w,
                                     pwb, qkvw, wow, w1w, w2w, projw,
                                     sino, st);
  bp_part<<<2048, 256, 0, stream>>>(st, lut, partial);

  mega2<<<GRID, 256, 0, stream>>>(
      partial, bpb, out + 262144,
      pwb, patch_b, pos, ln1_g, ln1_b, qkvw, bqkv, wow, bo,
      ln2_g, ln2_b, w1w, b1, w2w, b2, projw, proj_b, conv_w, conv_b,
      z, qkvb16, ob16, hb16, imgp, out, bar);
}

// Round 9
// 573.225 us; speedup vs baseline: 3.7399x; 3.7399x over previous
//
#include <hip/hip_runtime.h>
#include <hip/hip_bf16.h>
#include <math.h>

#define BB 4
#define NDET 128
#define NT 2048
#define DD 256
#define LL 6
#define MROWS 1024

typedef __attribute__((ext_vector_type(8))) short s8v;
typedef __attribute__((ext_vector_type(4))) float f32x4;
typedef unsigned short ushort_t;

__device__ __forceinline__ unsigned short f2b(float x) {
  union { float f; unsigned u; } v; v.f = x;
  unsigned r = v.u + 0x7fff + ((v.u >> 16) & 1);
  return (unsigned short)(r >> 16);
}
__device__ __forceinline__ unsigned pk2(float a, float b) {
  return (unsigned)f2b(a) | ((unsigned)f2b(b) << 16);
}
__device__ __forceinline__ float gelu_exact(float x) {
  return 0.5f * x * (1.0f + erff(x * 0.70710678118654752f));
}

// ---------------- prep: weight casts + sino transpose ----------------
__global__ __launch_bounds__(256) void cast_all(
    const float* __restrict__ s0, const float* __restrict__ s1,
    const float* __restrict__ s2, const float* __restrict__ s3,
    const float* __restrict__ s4, const float* __restrict__ s5,
    unsigned short* __restrict__ d0, unsigned short* __restrict__ d1,
    unsigned short* __restrict__ d2, unsigned short* __restrict__ d3,
    unsigned short* __restrict__ d4, unsigned short* __restrict__ d5,
    const float* __restrict__ sino, float* __restrict__ st)
{
  const int e0 = 16384, e1 = 311296, e2 = 409600, e3 = 802816, e4 = 1196032,
            e5 = 1212416, e6 = 1474560;
  int i = blockIdx.x * 256 + threadIdx.x;
  int stride = gridDim.x * 256;
  for (; i < e6; i += stride) {
    if (i < e5) {
      const float* s; unsigned short* d; int j;
      if (i < e0)      { s = s0; d = d0; j = i; }
      else if (i < e1) { s = s1; d = d1; j = i - e0; }
      else if (i < e2) { s = s2; d = d2; j = i - e1; }
      else if (i < e3) { s = s3; d = d3; j = i - e2; }
      else if (i < e4) { s = s4; d = d4; j = i - e3; }
      else             { s = s5; d = d5; j = i - e4; }
      float4 f = ((const float4*)s)[j];
      uint2 uv;
      uv.x = pk2(f.x, f.y);
      uv.y = pk2(f.z, f.w);
      ((uint2*)d)[j] = uv;
    } else {
      int idx = i - e5;
      float4 v;
      v.x = sino[idx];
      v.y = sino[262144 + idx];
      v.z = sino[524288 + idx];
      v.w = sino[786432 + idx];
      ((float4*)st)[idx] = v;
    }
  }
}

// ---------------- backprojection: XCD-pinned chunks, batched ILP ----------
__global__ __launch_bounds__(256) void bp_part(
    const float* __restrict__ st, const float* __restrict__ lut,
    float* __restrict__ partial)
{
  __shared__ float apod[NDET];
  int tid = threadIdx.x;
  if (tid < NDET) {
    float ap = 0.5f - 0.5f * cosf(6.283185307179586f * (float)tid / 127.0f);
    apod[tid] = ap * (1.0f / 63.5f);
  }
  __syncthreads();
  int c = blockIdx.x & 7;          // detector chunk -> XCD-pinned L2 slab
  int pb = blockIdx.x >> 3;
  int pix = pb * 256 + tid;
  const float4* lrow4 = (const float4*)(lut + (size_t)pix * 256);
  const float4* sp = (const float4*)st;
  float a0 = 0.f, a1 = 0.f, a2 = 0.f, a3 = 0.f;
#pragma unroll
  for (int half = 0; half < 2; ++half) {
    int d0 = c * 16 + half * 8;
    // 4 lut float4 loads in flight (8 detectors)
    float4 l0 = lrow4[d0 / 2 + 0];
    float4 l1 = lrow4[d0 / 2 + 1];
    float4 l2 = lrow4[d0 / 2 + 2];
    float4 l3 = lrow4[d0 / 2 + 3];
    float kfa[8] = {l0.x, l0.z, l1.x, l1.z, l2.x, l2.z, l3.x, l3.z};
    float ala[8] = {l0.y, l0.w, l1.y, l1.w, l2.y, l2.w, l3.y, l3.w};
    float4 sv0[8], sv1[8];
    float w0[8], w1[8];
    // branchless: all 16 gathers issued back-to-back
#pragma unroll
    for (int dd = 0; dd < 8; ++dd) {
      int kf = (int)kfa[dd];
      bool valid = (kf >= 0) && (kf < NT - 1);
      int kc = valid ? kf : 0;
      float ap = valid ? apod[d0 + dd] : 0.f;
      w0[dd] = (1.0f - ala[dd]) * ap;
      w1[dd] = ala[dd] * ap;
      const float4* q = sp + (d0 + dd) * NT + kc;
      sv0[dd] = q[0];
      sv1[dd] = q[1];
    }
#pragma unroll
    for (int dd = 0; dd < 8; ++dd) {
      a0 += w0[dd] * sv0[dd].x + w1[dd] * sv1[dd].x;
      a1 += w0[dd] * sv0[dd].y + w1[dd] * sv1[dd].y;
      a2 += w0[dd] * sv0[dd].z + w1[dd] * sv1[dd].z;
      a3 += w0[dd] * sv0[dd].w + w1[dd] * sv1[dd].w;
    }
  }
  partial[(size_t)(c * 4 + 0) * 65536 + pix] = a0;
  partial[(size_t)(c * 4 + 1) * 65536 + pix] = a1;
  partial[(size_t)(c * 4 + 2) * 65536 + pix] = a2;
  partial[(size_t)(c * 4 + 3) * 65536 + pix] = a3;
}

__global__ __launch_bounds__(256) void bp_reduce(
    const float* __restrict__ partial, float* __restrict__ bp,
    float* __restrict__ out_bp)
{
  int pix = blockIdx.x * 256 + threadIdx.x;
#pragma unroll
  for (int b = 0; b < 4; ++b) {
    float s = 0.f;
#pragma unroll
    for (int c = 0; c < 8; ++c) s += partial[(size_t)(c * 4 + b) * 65536 + pix];
    bp[b * 65536 + pix] = s;
    out_bp[b * 65536 + pix] = s;
  }
}

// ---------------- 32xTN bf16 MFMA GEMM, full-K LDS panels -----------------
// TN in {32, 64}. AMODE: 0 fp32 A, 1 gather bp image, 2 LN(A) fused, 3 bf16 A
// OMODE: 0 fp32 out, 1 scatter to image, 2 bf16 out
template<int ACT, int RES, int AMODE, int OMODE, int TN>
__global__ __launch_bounds__(256) void gemm4(
    const float* __restrict__ A, const unsigned short* __restrict__ A16,
    const unsigned short* __restrict__ Wb,
    const float* __restrict__ bias, const float* __restrict__ res,
    const float* __restrict__ lng, const float* __restrict__ lnb,
    float* __restrict__ C, unsigned short* __restrict__ C16,
    int N, int K, int res_mask)
{
  constexpr int NJ = TN / 32;
  __shared__ __align__(16) unsigned short As[32][264];
  __shared__ __align__(16) unsigned short Bs[TN][264];
  int bm = blockIdx.y * 32, bn = blockIdx.x * TN;
  int tid = threadIdx.x;
  int lane = tid & 63, w = tid >> 6;
  int lr = lane & 15, hi = lane >> 4;
  int lk = hi * 8, lg = hi * 4;
  int wr = (w & 1) * 16, wc = (w >> 1) * (TN / 2 == 32 ? 32 : 16);
  f32x4 acc[NJ];
#pragma unroll
  for (int j = 0; j < NJ; ++j) acc[j] = (f32x4){0.f, 0.f, 0.f, 0.f};

  for (int kc = 0; kc < K; kc += 256) {
    if (kc) __syncthreads();
    if (AMODE == 2) {
      float4 gl = ((const float4*)lng)[lane];
      float4 bl = ((const float4*)lnb)[lane];
#pragma unroll
      for (int rr = 0; rr < 8; ++rr) {
        int row = w * 8 + rr;
        float4 v = ((const float4*)(A + (size_t)(bm + row) * 256))[lane];
        float s = v.x + v.y + v.z + v.w;
#pragma unroll
        for (int off = 32; off; off >>= 1) s += __shfl_xor(s, off);
        float mean = s * (1.0f / 256.0f);
        float q = (v.x - mean) * (v.x - mean) + (v.y - mean) * (v.y - mean) +
                  (v.z - mean) * (v.z - mean) + (v.w - mean) * (v.w - mean);
#pragma unroll
        for (int off = 32; off; off >>= 1) q += __shfl_xor(q, off);
        float inv = 1.0f / sqrtf(q * (1.0f / 256.0f) + 1e-5f);
        float y0 = (v.x - mean) * inv * gl.x + bl.x;
        float y1 = (v.y - mean) * inv * gl.y + bl.y;
        float y2 = (v.z - mean) * inv * gl.z + bl.z;
        float y3 = (v.w - mean) * inv * gl.w + bl.w;
        uint2 u2; u2.x = pk2(y0, y1); u2.y = pk2(y2, y3);
        *(uint2*)&As[row][lane * 4] = u2;
      }
    } else if (AMODE == 3) {
      int r = tid >> 3, cb = (tid & 7) * 32;
      const unsigned short* ap = A16 + (size_t)(bm + r) * K + kc + cb;
#pragma unroll
      for (int q8 = 0; q8 < 4; ++q8)
        *(uint4*)&As[r][cb + q8 * 8] = *(const uint4*)(ap + q8 * 8);
    } else {
      int r = tid >> 3, cb = (tid & 7) * 32;
#pragma unroll
      for (int q8 = 0; q8 < 4; ++q8) {
        int k = cb + q8 * 8;
        float4 f0, f1;
        if (AMODE == 0) {
          const float* ap = A + (size_t)(bm + r) * K + kc + k;
          f0 = *(const float4*)ap;
          f1 = *(const float4*)(ap + 4);
        } else {
          int m = bm + r;
          int bb = m >> 8, nn = m & 255;
          int k2 = k + 4;
          f0 = *(const float4*)(A + (size_t)bb * 65536 +
               ((nn >> 4) * 16 + (k >> 4)) * 256 + (nn & 15) * 16 + (k & 15));
          f1 = *(const float4*)(A + (size_t)bb * 65536 +
               ((nn >> 4) * 16 + (k2 >> 4)) * 256 + (nn & 15) * 16 + (k2 & 15));
        }
        uint4 u;
        u.x = pk2(f0.x, f0.y); u.y = pk2(f0.z, f0.w);
        u.z = pk2(f1.x, f1.y); u.w = pk2(f1.z, f1.w);
        *(uint4*)&As[r][k] = u;
      }
    }
    if (TN == 64) {
      int r = tid >> 2, cb = (tid & 3) * 64;
      const unsigned short* wp = Wb + (size_t)(bn + r) * K + kc + cb;
#pragma unroll
      for (int q8 = 0; q8 < 8; ++q8)
        *(uint4*)&Bs[r][cb + q8 * 8] = *(const uint4*)(wp + q8 * 8);
    } else {
      int r = tid >> 3, cb = (tid & 7) * 32;
      const unsigned short* wp = Wb + (size_t)(bn + r) * K + kc + cb;
#pragma unroll
      for (int q8 = 0; q8 < 4; ++q8)
        *(uint4*)&Bs[r][cb + q8 * 8] = *(const uint4*)(wp + q8 * 8);
    }
    __syncthreads();
#pragma unroll
    for (int k0 = 0; k0 < 256; k0 += 32) {
      s8v a = *(const s8v*)&As[wr + lr][k0 + lk];
      s8v b0 = *(const s8v*)&Bs[wc + lr][k0 + lk];
      acc[0] = __builtin_amdgcn_mfma_f32_16x16x32_bf16(a, b0, acc[0], 0, 0, 0);
      if (NJ == 2) {
        s8v b1 = *(const s8v*)&Bs[wc + 16 + lr][k0 + lk];
        acc[1] = __builtin_amdgcn_mfma_f32_16x16x32_bf16(a, b1, acc[1], 0, 0, 0);
      }
    }
  }

#pragma unroll
  for (int j = 0; j < NJ; ++j) {
    int n = bn + wc + j * 16 + lr;
    float bv = bias[n];
#pragma unroll
    for (int r4 = 0; r4 < 4; ++r4) {
      int m = bm + wr + lg + r4;
      float c = acc[j][r4] + bv;
      if (ACT == 1) c = gelu_exact(c);
      if (RES == 1) c += res[(size_t)(m & res_mask) * N + n];
      if (OMODE == 0) {
        C[(size_t)m * N + n] = c;
      } else if (OMODE == 1) {
        int bb = m >> 8, t2 = m & 255;
        C[(size_t)bb * 65536 + ((t2 >> 4) * 16 + (n >> 4)) * 256 +
          (t2 & 15) * 16 + (n & 15)] = c;
      } else {
        C16[(size_t)m * N + n] = f2b(c);
      }
    }
  }
}

// ---------------- fused attention + WO + residual -------------------------
// grid 64 = (b, rc of 16 rows); loops over 8 heads; z += o @ wo^T + bo
__global__ __launch_bounds__(256) void attn_wo(
    const unsigned short* __restrict__ qkv,
    const unsigned short* __restrict__ wow, const float* __restrict__ bo,
    float* __restrict__ z)
{
  __shared__ __align__(16) char smem[71424];
  unsigned short (*Qb)[264] = (unsigned short(*)[264])(smem);          // 16 r
  unsigned short (*Kl)[40]  = (unsigned short(*)[40])(smem + 8448);    // 256 r
  unsigned short (*Vt)[264] = (unsigned short(*)[264])(smem + 28928);  // 32 r
  float (*Sf)[268]          = (float(*)[268])(smem + 45824);           // 16 r
  unsigned short (*Pl)[264] = (unsigned short(*)[264])(smem + 45824);  // alias
  unsigned short (*Ob)[264] = (unsigned short(*)[264])(smem + 62976);  // 16 r
  unsigned short (*Bs)[264] = (unsigned short(*)[264])(smem + 8448);   // alias

  int bi = blockIdx.x;
  int rc = bi & 15, b = bi >> 4;
  int tid = threadIdx.x, lane = tid & 63, w = tid >> 6;
  int lr = lane & 15, hi = lane >> 4;
  int lk = hi * 8, lg = hi * 4;
  int m0 = b * 256 + rc * 16;
  const unsigned short* base = qkv + (size_t)b * 256 * 768;

  {  // stage Q: 16 rows x 256 cols
    int r = tid >> 4, c0 = (tid & 15) * 16;
    const unsigned short* qp = base + (size_t)(rc * 16 + r) * 768 + c0;
    *(uint4*)&Qb[r][c0] = *(const uint4*)qp;
    *(uint4*)&Qb[r][c0 + 8] = *(const uint4*)(qp + 8);
  }

  for (int h = 0; h < 8; ++h) {
    __syncthreads();
    {  // stage K_h (row tid), V_h (transposed)
      const unsigned short* kr = base + (size_t)tid * 768 + 256 + h * 32;
      *(uint4*)&Kl[tid][0]  = *(const uint4*)kr;
      *(uint4*)&Kl[tid][8]  = *(const uint4*)(kr + 8);
      *(uint4*)&Kl[tid][16] = *(const uint4*)(kr + 16);
      *(uint4*)&Kl[tid][24] = *(const uint4*)(kr + 24);
      const unsigned short* vr = base + (size_t)tid * 768 + 512 + h * 32;
      unsigned short tmp[32];
      *(uint4*)&tmp[0]  = *(const uint4*)vr;
      *(uint4*)&tmp[8]  = *(const uint4*)(vr + 8);
      *(uint4*)&tmp[16] = *(const uint4*)(vr + 16);
      *(uint4*)&tmp[24] = *(const uint4*)(vr + 24);
#pragma unroll
      for (int cc = 0; cc < 32; ++cc) Vt[cc][tid] = tmp[cc];
    }
    __syncthreads();
    {  // QK^T: wave w covers score cols w*64..+63
      s8v qa = *(const s8v*)&Qb[lr][h * 32 + lk];
      f32x4 z4 = (f32x4){0.f, 0.f, 0.f, 0.f};
#pragma unroll
      for (int j = 0; j < 4; ++j) {
        s8v kb = *(const s8v*)&Kl[w * 64 + j * 16 + lr][lk];
        f32x4 s0 = __builtin_amdgcn_mfma_f32_16x16x32_bf16(qa, kb, z4, 0, 0, 0);
#pragma unroll
        for (int r4 = 0; r4 < 4; ++r4)
          Sf[lg + r4][w * 64 + j * 16 + lr] = s0[r4];
      }
    }
    __syncthreads();
    // softmax: wave w rows w*4..w*4+3
    float vv[4][4];
    {
      const float scale = 0.17677669529663687f;
#pragma unroll
      for (int rr = 0; rr < 4; ++rr) {
        int row = w * 4 + rr;
        float4 v = *(const float4*)&Sf[row][lane * 4];
        v.x *= scale; v.y *= scale; v.z *= scale; v.w *= scale;
        float mx = fmaxf(fmaxf(v.x, v.y), fmaxf(v.z, v.w));
#pragma unroll
        for (int off = 32; off; off >>= 1) mx = fmaxf(mx, __shfl_xor(mx, off));
        float e0 = expf(v.x - mx), e1 = expf(v.y - mx);
        float e2 = expf(v.z - mx), e3 = expf(v.w - mx);
        float ss = e0 + e1 + e2 + e3;
#pragma unroll
        for (int off = 32; off; off >>= 1) ss += __shfl_xor(ss, off);
        float inv = 1.0f / ss;
        vv[rr][0] = e0 * inv; vv[rr][1] = e1 * inv;
        vv[rr][2] = e2 * inv; vv[rr][3] = e3 * inv;
      }
    }
    __syncthreads();
#pragma unroll
    for (int rr = 0; rr < 4; ++rr) {
      uint2 u2;
      u2.x = pk2(vv[rr][0], vv[rr][1]);
      u2.y = pk2(vv[rr][2], vv[rr][3]);
      *(uint2*)&Pl[w * 4 + rr][lane * 4] = u2;
    }
    __syncthreads();
    if (w < 2) {  // PV: wave w -> V cols w*16..+15
      f32x4 oa = (f32x4){0.f, 0.f, 0.f, 0.f};
#pragma unroll
      for (int ks = 0; ks < 8; ++ks) {
        s8v pa = *(const s8v*)&Pl[lr][ks * 32 + lk];
        s8v vb = *(const s8v*)&Vt[w * 16 + lr][ks * 32 + lk];
        oa = __builtin_amdgcn_mfma_f32_16x16x32_bf16(pa, vb, oa, 0, 0, 0);
      }
#pragma unroll
      for (int r4 = 0; r4 < 4; ++r4)
        Ob[lg + r4][h * 32 + w * 16 + lr] = f2b(oa[r4]);
    }
  }
  __syncthreads();

  // WO: z(16x256) += Ob @ wow^T + bo
  for (int nc = 0; nc < 4; ++nc) {
    __syncthreads();
    {
      int r = tid >> 2, cb = (tid & 3) * 64;
      const unsigned short* wp = wow + (size_t)(nc * 64 + r) * 256 + cb;
#pragma unroll
      for (int q8 = 0; q8 < 8; ++q8)
        *(uint4*)&Bs[r][cb + q8 * 8] = *(const uint4*)(wp + q8 * 8);
    }
    __syncthreads();
    f32x4 acc = (f32x4){0.f, 0.f, 0.f, 0.f};
    int wc = w * 16;
#pragma unroll
    for (int k0 = 0; k0 < 256; k0 += 32) {
      s8v a = *(const s8v*)&Ob[lr][k0 + lk];
      s8v bb = *(const s8v*)&Bs[wc + lr][k0 + lk];
      acc = __builtin_amdgcn_mfma_f32_16x16x32_bf16(a, bb, acc, 0, 0, 0);
    }
    int n = nc * 64 + wc + lr;
    float bv = bo[n];
#pragma unroll
    for (int r4 = 0; r4 < 4; ++r4) {
      int m = m0 + lg + r4;
      z[(size_t)m * 256 + n] += acc[r4] + bv;
    }
  }
}

// ---------------- conv 3x3 SAME + conv_b + bp residual --------------------
__global__ __launch_bounds__(256) void conv_kernel(
    const float* __restrict__ img, const float* __restrict__ cw,
    const float* __restrict__ cb, const float* __restrict__ bp,
    float* __restrict__ out_img)
{
  int gid = blockIdx.x * 256 + threadIdx.x;
  int b = gid >> 16, rem = gid & 65535;
  int y = rem >> 8, x = rem & 255;
  const float* ip = img + (size_t)b * 65536;
  float s = cb[0];
#pragma unroll
  for (int dy = -1; dy <= 1; ++dy)
#pragma unroll
    for (int dx = -1; dx <= 1; ++dx) {
      int yy = y + dy, xx = x + dx;
      if (yy >= 0 && yy < 256 && xx >= 0 && xx < 256)
        s += cw[(dy + 1) * 3 + (dx + 1)] * ip[yy * 256 + xx];
    }
  out_img[gid] = s + bp[gid];
}

extern "C" void kernel_launch(void* const* d_in, const int* in_sizes, int n_in,
                              void* d_out, int out_size, void* d_ws, size_t ws_size,
                              hipStream_t stream) {
  const float* sino    = (const float*)d_in[0];
  const float* lut     = (const float*)d_in[1];
  const float* patch_w = (const float*)d_in[2];
  const float* patch_b = (const float*)d_in[3];
  const float* pos     = (const float*)d_in[4];
  const float* ln1_g   = (const float*)d_in[5];
  const float* ln1_b   = (const float*)d_in[6];
  const float* wqkv    = (const float*)d_in[7];
  const float* bqkv    = (const float*)d_in[8];
  const float* wo      = (const float*)d_in[9];
  const float* bo      = (const float*)d_in[10];
  const float* ln2_g   = (const float*)d_in[11];
  const float* ln2_b   = (const float*)d_in[12];
  const float* w1      = (const float*)d_in[13];
  const float* b1      = (const float*)d_in[14];
  const float* w2      = (const float*)d_in[15];
  const float* b2      = (const float*)d_in[16];
  const float* proj_w  = (const float*)d_in[17];
  const float* proj_b  = (const float*)d_in[18];
  const float* conv_w  = (const float*)d_in[19];
  const float* conv_b  = (const float*)d_in[20];
  float* out = (float*)d_out;
  float* ws  = (float*)d_ws;

  // fp32 scratch
  float* bpb     = ws;                   // 262144
  float* z       = bpb + 262144;         // 262144
  float* imgp    = z + 262144;           // 262144
  float* partial = imgp + 262144;        // 2097152
  float* st      = partial + 2097152;    // 1048576
  // bf16 region
  unsigned short* wsu    = (unsigned short*)(st + 1048576);
  unsigned short* pwb    = wsu;                 // 65536
  unsigned short* qkvw   = pwb + 65536;         // 1179648
  unsigned short* wow    = qkvw + 1179648;      // 393216
  unsigned short* w1w    = wow + 393216;        // 1572864
  unsigned short* w2w    = w1w + 1572864;       // 1572864
  unsigned short* projw  = w2w + 1572864;       // 65536
  unsigned short* qkvb16 = projw + 65536;       // 786432
  unsigned short* hb16   = qkvb16 + 786432;     // 1048576

  cast_all<<<2048, 256, 0, stream>>>(patch_w, wqkv, wo, w1, w2, proj_w,
                                     pwb, qkvw, wow, w1w, w2w, projw,
                                     sino, st);
  bp_part<<<2048, 256, 0, stream>>>(st, lut, partial);
  bp_reduce<<<256, 256, 0, stream>>>(partial, bpb, out + 262144);

  // patch embed (gather from image) + pos_embed
  gemm4<0, 1, 1, 0, 32><<<dim3(8, 32), 256, 0, stream>>>(
      bpb, nullptr, pwb, patch_b, pos, nullptr, nullptr, z, nullptr,
      256, 256, 255);

  for (int l = 0; l < LL; ++l) {
    // LN1 + QKV -> bf16
    gemm4<0, 0, 2, 2, 64><<<dim3(12, 32), 256, 0, stream>>>(
        z, nullptr, qkvw + (size_t)l * 196608, bqkv + l * 768, nullptr,
        ln1_g + l * 256, ln1_b + l * 256, nullptr, qkvb16, 768, 256, 0);
    // fused attention + WO + residual
    attn_wo<<<64, 256, 0, stream>>>(qkvb16, wow + (size_t)l * 65536,
                                    bo + l * 256, z);
    // LN2 + FC1 + gelu -> bf16
    gemm4<1, 0, 2, 2, 64><<<dim3(16, 32), 256, 0, stream>>>(
        z, nullptr, w1w + (size_t)l * 262144, b1 + l * 1024, nullptr,
        ln2_g + l * 256, ln2_b + l * 256, nullptr, hb16, 1024, 256, 0);
    // FC2 + residual (A = gelu out bf16, K=1024)
    gemm4<0, 1, 3, 0, 32><<<dim3(8, 32), 256, 0, stream>>>(
        nullptr, hb16, w2w + (size_t)l * 262144, b2 + l * 256, z,
        nullptr, nullptr, z, nullptr, 256, 1024, 1023);
  }

  // proj scattered into image layout, then conv + bp residual
  gemm4<0, 0, 0, 1, 32><<<dim3(8, 32), 256, 0, stream>>>(
      z, nullptr, projw, proj_b, nullptr, nullptr, nullptr, imgp, nullptr,
      256, 256, 0);
  conv_kernel<<<1024, 256, 0, stream>>>(imgp, conv_w, conv_b, bpb, out);
}

// Round 10
// 425.732 us; speedup vs baseline: 5.0356x; 1.3464x over previous
//
#include <hip/hip_runtime.h>
#include <hip/hip_bf16.h>
#include <math.h>

#define BB 4
#define NDET 128
#define NT 2048
#define DD 256
#define LL 6
#define MROWS 1024

typedef __attribute__((ext_vector_type(8))) short s8v;
typedef __attribute__((ext_vector_type(4))) float f32x4;
typedef unsigned short ushort_t;

__device__ __forceinline__ unsigned short f2b(float x) {
  union { float f; unsigned u; } v; v.f = x;
  unsigned r = v.u + 0x7fff + ((v.u >> 16) & 1);
  return (unsigned short)(r >> 16);
}
__device__ __forceinline__ unsigned pk2(float a, float b) {
  return (unsigned)f2b(a) | ((unsigned)f2b(b) << 16);
}
__device__ __forceinline__ float gelu_exact(float x) {
  return 0.5f * x * (1.0f + erff(x * 0.70710678118654752f));
}

// ---------------- prep: weight casts + sino transpose ----------------
__global__ __launch_bounds__(256) void cast_all(
    const float* __restrict__ s0, const float* __restrict__ s1,
    const float* __restrict__ s2, const float* __restrict__ s3,
    const float* __restrict__ s4, const float* __restrict__ s5,
    unsigned short* __restrict__ d0, unsigned short* __restrict__ d1,
    unsigned short* __restrict__ d2, unsigned short* __restrict__ d3,
    unsigned short* __restrict__ d4, unsigned short* __restrict__ d5,
    const float* __restrict__ sino, float* __restrict__ st)
{
  const int e0 = 16384, e1 = 311296, e2 = 409600, e3 = 802816, e4 = 1196032,
            e5 = 1212416, e6 = 1474560;
  int i = blockIdx.x * 256 + threadIdx.x;
  int stride = gridDim.x * 256;
  for (; i < e6; i += stride) {
    if (i < e5) {
      const float* s; unsigned short* d; int j;
      if (i < e0)      { s = s0; d = d0; j = i; }
      else if (i < e1) { s = s1; d = d1; j = i - e0; }
      else if (i < e2) { s = s2; d = d2; j = i - e1; }
      else if (i < e3) { s = s3; d = d3; j = i - e2; }
      else if (i < e4) { s = s4; d = d4; j = i - e3; }
      else             { s = s5; d = d5; j = i - e4; }
      float4 f = ((const float4*)s)[j];
      uint2 uv;
      uv.x = pk2(f.x, f.y);
      uv.y = pk2(f.z, f.w);
      ((uint2*)d)[j] = uv;
    } else {
      int idx = i - e5;
      float4 v;
      v.x = sino[idx];
      v.y = sino[262144 + idx];
      v.z = sino[524288 + idx];
      v.w = sino[786432 + idx];
      ((float4*)st)[idx] = v;
    }
  }
}

// ---------------- backprojection: XCD-pinned chunks, batched ILP ----------
__global__ __launch_bounds__(256) void bp_part(
    const float* __restrict__ st, const float* __restrict__ lut,
    float* __restrict__ partial)
{
  __shared__ float apod[NDET];
  int tid = threadIdx.x;
  if (tid < NDET) {
    float ap = 0.5f - 0.5f * cosf(6.283185307179586f * (float)tid / 127.0f);
    apod[tid] = ap * (1.0f / 63.5f);
  }
  __syncthreads();
  int c = blockIdx.x & 7;          // detector chunk -> XCD-pinned L2 slab
  int pb = blockIdx.x >> 3;
  int pix = pb * 256 + tid;
  const float4* lrow4 = (const float4*)(lut + (size_t)pix * 256);
  const float4* sp = (const float4*)st;
  float a0 = 0.f, a1 = 0.f, a2 = 0.f, a3 = 0.f;
#pragma unroll
  for (int half = 0; half < 2; ++half) {
    int d0 = c * 16 + half * 8;
    float4 l0 = lrow4[d0 / 2 + 0];
    float4 l1 = lrow4[d0 / 2 + 1];
    float4 l2 = lrow4[d0 / 2 + 2];
    float4 l3 = lrow4[d0 / 2 + 3];
    float kfa[8] = {l0.x, l0.z, l1.x, l1.z, l2.x, l2.z, l3.x, l3.z};
    float ala[8] = {l0.y, l0.w, l1.y, l1.w, l2.y, l2.w, l3.y, l3.w};
    float4 sv0[8], sv1[8];
    float w0[8], w1[8];
#pragma unroll
    for (int dd = 0; dd < 8; ++dd) {
      int kf = (int)kfa[dd];
      bool valid = (kf >= 0) && (kf < NT - 1);
      int kc = valid ? kf : 0;
      float ap = valid ? apod[d0 + dd] : 0.f;
      w0[dd] = (1.0f - ala[dd]) * ap;
      w1[dd] = ala[dd] * ap;
      const float4* q = sp + (d0 + dd) * NT + kc;
      sv0[dd] = q[0];
      sv1[dd] = q[1];
    }
#pragma unroll
    for (int dd = 0; dd < 8; ++dd) {
      a0 += w0[dd] * sv0[dd].x + w1[dd] * sv1[dd].x;
      a1 += w0[dd] * sv0[dd].y + w1[dd] * sv1[dd].y;
      a2 += w0[dd] * sv0[dd].z + w1[dd] * sv1[dd].z;
      a3 += w0[dd] * sv0[dd].w + w1[dd] * sv1[dd].w;
    }
  }
  partial[(size_t)(c * 4 + 0) * 65536 + pix] = a0;
  partial[(size_t)(c * 4 + 1) * 65536 + pix] = a1;
  partial[(size_t)(c * 4 + 2) * 65536 + pix] = a2;
  partial[(size_t)(c * 4 + 3) * 65536 + pix] = a3;
}

// ---------------- bp reduce: also emits patchified bf16 A -----------------
__global__ __launch_bounds__(256) void bp_reduce(
    const float* __restrict__ partial, float* __restrict__ bp,
    float* __restrict__ out_bp, unsigned short* __restrict__ xp16)
{
  int pix = blockIdx.x * 256 + threadIdx.x;
  int y = pix >> 8, x = pix & 255;
  int tok = (y >> 4) * 16 + (x >> 4);
  int pp = (y & 15) * 16 + (x & 15);
#pragma unroll
  for (int b = 0; b < 4; ++b) {
    float s = 0.f;
#pragma unroll
    for (int c = 0; c < 8; ++c) s += partial[(size_t)(c * 4 + b) * 65536 + pix];
    bp[b * 65536 + pix] = s;
    out_bp[b * 65536 + pix] = s;
    xp16[((size_t)(b * 256 + tok)) * 256 + pp] = f2b(s);
  }
}

// ---------------- 32xTN bf16 MFMA GEMM, full-K LDS panels -----------------
// AMODE: 0 fp32 A, 2 LN(A) fused, 3 bf16 A
// OMODE: 0 fp32 out, 1 scatter to image, 2 bf16 out
template<int ACT, int RES, int AMODE, int OMODE, int TN>
__global__ __launch_bounds__(256) void gemm4(
    const float* __restrict__ A, const unsigned short* __restrict__ A16,
    const unsigned short* __restrict__ Wb,
    const float* __restrict__ bias, const float* __restrict__ res,
    const float* __restrict__ lng, const float* __restrict__ lnb,
    float* __restrict__ C, unsigned short* __restrict__ C16,
    int N, int K, int res_mask)
{
  constexpr int NJ = TN / 32;
  __shared__ __align__(16) unsigned short As[32][264];
  __shared__ __align__(16) unsigned short Bs[TN][264];
  int bm = blockIdx.y * 32, bn = blockIdx.x * TN;
  int tid = threadIdx.x;
  int lane = tid & 63, w = tid >> 6;
  int lr = lane & 15, hi = lane >> 4;
  int lk = hi * 8, lg = hi * 4;
  int wr = (w & 1) * 16, wc = (w >> 1) * (TN / 2 == 32 ? 32 : 16);
  f32x4 acc[NJ];
#pragma unroll
  for (int j = 0; j < NJ; ++j) acc[j] = (f32x4){0.f, 0.f, 0.f, 0.f};

  for (int kc = 0; kc < K; kc += 256) {
    if (kc) __syncthreads();
    if (AMODE == 2) {
      float4 gl = ((const float4*)lng)[lane];
      float4 bl = ((const float4*)lnb)[lane];
#pragma unroll
      for (int rr = 0; rr < 8; ++rr) {
        int row = w * 8 + rr;
        float4 v = ((const float4*)(A + (size_t)(bm + row) * 256))[lane];
        float s = v.x + v.y + v.z + v.w;
#pragma unroll
        for (int off = 32; off; off >>= 1) s += __shfl_xor(s, off);
        float mean = s * (1.0f / 256.0f);
        float q = (v.x - mean) * (v.x - mean) + (v.y - mean) * (v.y - mean) +
                  (v.z - mean) * (v.z - mean) + (v.w - mean) * (v.w - mean);
#pragma unroll
        for (int off = 32; off; off >>= 1) q += __shfl_xor(q, off);
        float inv = 1.0f / sqrtf(q * (1.0f / 256.0f) + 1e-5f);
        float y0 = (v.x - mean) * inv * gl.x + bl.x;
        float y1 = (v.y - mean) * inv * gl.y + bl.y;
        float y2 = (v.z - mean) * inv * gl.z + bl.z;
        float y3 = (v.w - mean) * inv * gl.w + bl.w;
        uint2 u2; u2.x = pk2(y0, y1); u2.y = pk2(y2, y3);
        *(uint2*)&As[row][lane * 4] = u2;
      }
    } else if (AMODE == 3) {
      int r = tid >> 3, cb = (tid & 7) * 32;
      const unsigned short* ap = A16 + (size_t)(bm + r) * K + kc + cb;
#pragma unroll
      for (int q8 = 0; q8 < 4; ++q8)
        *(uint4*)&As[r][cb + q8 * 8] = *(const uint4*)(ap + q8 * 8);
    } else {
      int r = tid >> 3, cb = (tid & 7) * 32;
#pragma unroll
      for (int q8 = 0; q8 < 4; ++q8) {
        int k = cb + q8 * 8;
        const float* ap = A + (size_t)(bm + r) * K + kc + k;
        float4 f0 = *(const float4*)ap;
        float4 f1 = *(const float4*)(ap + 4);
        uint4 u;
        u.x = pk2(f0.x, f0.y); u.y = pk2(f0.z, f0.w);
        u.z = pk2(f1.x, f1.y); u.w = pk2(f1.z, f1.w);
        *(uint4*)&As[r][k] = u;
      }
    }
    if (TN == 64) {
      int r = tid >> 2, cb = (tid & 3) * 64;
      const unsigned short* wp = Wb + (size_t)(bn + r) * K + kc + cb;
#pragma unroll
      for (int q8 = 0; q8 < 8; ++q8)
        *(uint4*)&Bs[r][cb + q8 * 8] = *(const uint4*)(wp + q8 * 8);
    } else {
      int r = tid >> 3, cb = (tid & 7) * 32;
      const unsigned short* wp = Wb + (size_t)(bn + r) * K + kc + cb;
#pragma unroll
      for (int q8 = 0; q8 < 4; ++q8)
        *(uint4*)&Bs[r][cb + q8 * 8] = *(const uint4*)(wp + q8 * 8);
    }
    __syncthreads();
#pragma unroll
    for (int k0 = 0; k0 < 256; k0 += 32) {
      s8v a = *(const s8v*)&As[wr + lr][k0 + lk];
      s8v b0 = *(const s8v*)&Bs[wc + lr][k0 + lk];
      acc[0] = __builtin_amdgcn_mfma_f32_16x16x32_bf16(a, b0, acc[0], 0, 0, 0);
      if (NJ == 2) {
        s8v b1 = *(const s8v*)&Bs[wc + 16 + lr][k0 + lk];
        acc[1] = __builtin_amdgcn_mfma_f32_16x16x32_bf16(a, b1, acc[1], 0, 0, 0);
      }
    }
  }

#pragma unroll
  for (int j = 0; j < NJ; ++j) {
    int n = bn + wc + j * 16 + lr;
    float bv = bias[n];
#pragma unroll
    for (int r4 = 0; r4 < 4; ++r4) {
      int m = bm + wr + lg + r4;
      float c = acc[j][r4] + bv;
      if (ACT == 1) c = gelu_exact(c);
      if (RES == 1) c += res[(size_t)(m & res_mask) * N + n];
      if (OMODE == 0) {
        C[(size_t)m * N + n] = c;
      } else if (OMODE == 1) {
        int bb = m >> 8, t2 = m & 255;
        C[(size_t)bb * 65536 + ((t2 >> 4) * 16 + (n >> 4)) * 256 +
          (t2 & 15) * 16 + (n & 15)] = c;
      } else {
        C16[(size_t)m * N + n] = f2b(c);
      }
    }
  }
}

// ---------------- fused attention (74 KB LDS, 256 blocks) -----------------
__global__ __launch_bounds__(256) void attn_fused(
    const unsigned short* __restrict__ qkv, unsigned short* __restrict__ o16)
{
  __shared__ __align__(16) unsigned short Kl[256][40];   // 20480
  __shared__ __align__(16) unsigned short Qb[32][40];    // 2560
  __shared__ __align__(16) unsigned short Vt[32][264];   // 16896
  __shared__ __align__(16) char sp[34304];               // Sf / Pl aliased
  float (*Sf)[268] = (float(*)[268])sp;
  unsigned short (*Pl)[264] = (unsigned short(*)[264])sp;
  int bi = blockIdx.x;
  int qc = bi & 7, h = (bi >> 3) & 7, b = bi >> 6;
  int tid = threadIdx.x, lane = tid & 63, w = tid >> 6;
  int lr = lane & 15, hi = lane >> 4;
  int lk = hi * 8, lg = hi * 4;
  const unsigned short* base = qkv + (size_t)b * 256 * 768;

  {
    const unsigned short* kr = base + tid * 768 + 256 + h * 32;
#pragma unroll
    for (int cq = 0; cq < 4; ++cq)
      *(uint4*)&Kl[tid][cq * 8] = *(const uint4*)(kr + cq * 8);
    const unsigned short* vr = base + tid * 768 + 512 + h * 32;
    unsigned short tmp[32];
#pragma unroll
    for (int cq = 0; cq < 4; ++cq)
      *(uint4*)&tmp[cq * 8] = *(const uint4*)(vr + cq * 8);
#pragma unroll
    for (int cc = 0; cc < 32; ++cc) Vt[cc][tid] = tmp[cc];
    int row = tid >> 3, c0 = (tid & 7) * 4;
    *(uint2*)&Qb[row][c0] =
        *(const uint2*)(base + (qc * 32 + row) * 768 + h * 32 + c0);
  }
  __syncthreads();

  {
    s8v qa0 = *(const s8v*)&Qb[lr][lk];
    s8v qa1 = *(const s8v*)&Qb[16 + lr][lk];
    f32x4 z4 = (f32x4){0.f, 0.f, 0.f, 0.f};
#pragma unroll
    for (int j = 0; j < 4; ++j) {
      s8v kb = *(const s8v*)&Kl[w * 64 + j * 16 + lr][lk];
      f32x4 s0 = __builtin_amdgcn_mfma_f32_16x16x32_bf16(qa0, kb, z4, 0, 0, 0);
      f32x4 s1 = __builtin_amdgcn_mfma_f32_16x16x32_bf16(qa1, kb, z4, 0, 0, 0);
#pragma unroll
      for (int r4 = 0; r4 < 4; ++r4) {
        Sf[lg + r4][w * 64 + j * 16 + lr] = s0[r4];
        Sf[16 + lg + r4][w * 64 + j * 16 + lr] = s1[r4];
      }
    }
  }
  __syncthreads();

  float vv[8][4];
  {
    const float scale = 0.17677669529663687f;
#pragma unroll
    for (int rr = 0; rr < 8; ++rr) {
      int row = w * 8 + rr;
      float4 v = *(const float4*)&Sf[row][lane * 4];
      v.x *= scale; v.y *= scale; v.z *= scale; v.w *= scale;
      float mx = fmaxf(fmaxf(v.x, v.y), fmaxf(v.z, v.w));
#pragma unroll
      for (int off = 32; off; off >>= 1) mx = fmaxf(mx, __shfl_xor(mx, off));
      float e0 = expf(v.x - mx), e1 = expf(v.y - mx);
      float e2 = expf(v.z - mx), e3 = expf(v.w - mx);
      float ss = e0 + e1 + e2 + e3;
#pragma unroll
      for (int off = 32; off; off >>= 1) ss += __shfl_xor(ss, off);
      float inv = 1.0f / ss;
      vv[rr][0] = e0 * inv; vv[rr][1] = e1 * inv;
      vv[rr][2] = e2 * inv; vv[rr][3] = e3 * inv;
    }
  }
  __syncthreads();
#pragma unroll
  for (int rr = 0; rr < 8; ++rr) {
    int row = w * 8 + rr;
    uint2 u2;
    u2.x = pk2(vv[rr][0], vv[rr][1]);
    u2.y = pk2(vv[rr][2], vv[rr][3]);
    *(uint2*)&Pl[row][lane * 4] = u2;
  }
  __syncthreads();

  {
    int wr = (w & 1) * 16, wc2 = (w >> 1) * 16;
    f32x4 oa = (f32x4){0.f, 0.f, 0.f, 0.f};
#pragma unroll
    for (int ks = 0; ks < 8; ++ks) {
      s8v pa = *(const s8v*)&Pl[wr + lr][ks * 32 + lk];
      s8v vb = *(const s8v*)&Vt[wc2 + lr][ks * 32 + lk];
      oa = __builtin_amdgcn_mfma_f32_16x16x32_bf16(pa, vb, oa, 0, 0, 0);
    }
#pragma unroll
    for (int r4 = 0; r4 < 4; ++r4) {
      int row = qc * 32 + wr + lg + r4;
      o16[((size_t)(b * 256) + row) * 256 + h * 32 + wc2 + lr] = f2b(oa[r4]);
    }
  }
}

// ---------------- conv 3x3 SAME + conv_b + bp residual --------------------
__global__ __launch_bounds__(256) void conv_kernel(
    const float* __restrict__ img, const float* __restrict__ cw,
    const float* __restrict__ cb, const float* __restrict__ bp,
    float* __restrict__ out_img)
{
  int gid = blockIdx.x * 256 + threadIdx.x;
  int b = gid >> 16, rem = gid & 65535;
  int y = rem >> 8, x = rem & 255;
  const float* ip = img + (size_t)b * 65536;
  float s = cb[0];
#pragma unroll
  for (int dy = -1; dy <= 1; ++dy)
#pragma unroll
    for (int dx = -1; dx <= 1; ++dx) {
      int yy = y + dy, xx = x + dx;
      if (yy >= 0 && yy < 256 && xx >= 0 && xx < 256)
        s += cw[(dy + 1) * 3 + (dx + 1)] * ip[yy * 256 + xx];
    }
  out_img[gid] = s + bp[gid];
}

extern "C" void kernel_launch(void* const* d_in, const int* in_sizes, int n_in,
                              void* d_out, int out_size, void* d_ws, size_t ws_size,
                              hipStream_t stream) {
  const float* sino    = (const float*)d_in[0];
  const float* lut     = (const float*)d_in[1];
  const float* patch_w = (const float*)d_in[2];
  const float* patch_b = (const float*)d_in[3];
  const float* pos     = (const float*)d_in[4];
  const float* ln1_g   = (const float*)d_in[5];
  const float* ln1_b   = (const float*)d_in[6];
  const float* wqkv    = (const float*)d_in[7];
  const float* bqkv    = (const float*)d_in[8];
  const float* wo      = (const float*)d_in[9];
  const float* bo      = (const float*)d_in[10];
  const float* ln2_g   = (const float*)d_in[11];
  const float* ln2_b   = (const float*)d_in[12];
  const float* w1      = (const float*)d_in[13];
  const float* b1      = (const float*)d_in[14];
  const float* w2      = (const float*)d_in[15];
  const float* b2      = (const float*)d_in[16];
  const float* proj_w  = (const float*)d_in[17];
  const float* proj_b  = (const float*)d_in[18];
  const float* conv_w  = (const float*)d_in[19];
  const float* conv_b  = (const float*)d_in[20];
  float* out = (float*)d_out;
  float* ws  = (float*)d_ws;

  // fp32 scratch
  float* bpb     = ws;                   // 262144
  float* z       = bpb + 262144;         // 262144
  float* imgp    = z + 262144;           // 262144
  float* partial = imgp + 262144;        // 2097152
  float* st      = partial + 2097152;    // 1048576
  // bf16 region
  unsigned short* wsu    = (unsigned short*)(st + 1048576);
  unsigned short* pwb    = wsu;                 // 65536
  unsigned short* qkvw   = pwb + 65536;         // 1179648
  unsigned short* wow    = qkvw + 1179648;      // 393216
  unsigned short* w1w    = wow + 393216;        // 1572864
  unsigned short* w2w    = w1w + 1572864;       // 1572864
  unsigned short* projw  = w2w + 1572864;       // 65536
  unsigned short* qkvb16 = projw + 65536;       // 786432
  unsigned short* hb16   = qkvb16 + 786432;     // 1048576
  unsigned short* ob16   = hb16 + 1048576;      // 262144
  unsigned short* xp16   = ob16 + 262144;       // 262144

  cast_all<<<2048, 256, 0, stream>>>(patch_w, wqkv, wo, w1, w2, proj_w,
                                     pwb, qkvw, wow, w1w, w2w, projw,
                                     sino, st);
  bp_part<<<2048, 256, 0, stream>>>(st, lut, partial);
  bp_reduce<<<256, 256, 0, stream>>>(partial, bpb, out + 262144, xp16);

  // patch embed (bf16 patchified A) + pos_embed
  gemm4<0, 1, 3, 0, 32><<<dim3(8, 32), 256, 0, stream>>>(
      nullptr, xp16, pwb, patch_b, pos, nullptr, nullptr, z, nullptr,
      256, 256, 255);

  for (int l = 0; l < LL; ++l) {
    // LN1 + QKV -> bf16
    gemm4<0, 0, 2, 2, 64><<<dim3(12, 32), 256, 0, stream>>>(
        z, nullptr, qkvw + (size_t)l * 196608, bqkv + l * 768, nullptr,
        ln1_g + l * 256, ln1_b + l * 256, nullptr, qkvb16, 768, 256, 0);
    attn_fused<<<256, 256, 0, stream>>>(qkvb16, ob16);
    // WO + residual (A = attn out bf16)
    gemm4<0, 1, 3, 0, 32><<<dim3(8, 32), 256, 0, stream>>>(
        nullptr, ob16, wow + (size_t)l * 65536, bo + l * 256, z,
        nullptr, nullptr, z, nullptr, 256, 256, 1023);
    // LN2 + FC1 + gelu -> bf16
    gemm4<1, 0, 2, 2, 64><<<dim3(16, 32), 256, 0, stream>>>(
        z, nullptr, w1w + (size_t)l * 262144, b1 + l * 1024, nullptr,
        ln2_g + l * 256, ln2_b + l * 256, nullptr, hb16, 1024, 256, 0);
    // FC2 + residual (A = gelu out bf16, K=1024)
    gemm4<0, 1, 3, 0, 32><<<dim3(8, 32), 256, 0, stream>>>(
        nullptr, hb16, w2w + (size_t)l * 262144, b2 + l * 256, z,
        nullptr, nullptr, z, nullptr, 256, 1024, 1023);
  }

  // proj scattered into image layout, then conv + bp residual
  gemm4<0, 0, 0, 1, 32><<<dim3(8, 32), 256, 0, stream>>>(
      z, nullptr, projw, proj_b, nullptr, nullptr, nullptr, imgp, nullptr,
      256, 256, 0);
  conv_kernel<<<1024, 256, 0, stream>>>(imgp, conv_w, conv_b, bpb, out);
}